// Round 9
// baseline (318.711 us; speedup 1.0000x reference)
//
#include <hip/hip_runtime.h>

// ---------------------------------------------------------------------------
// WindowAttention for MI355X (gfx950) — R8: two-kernel split
// B=1024 windows, N=64 tokens, C=256, H=8 heads, hd=32
// K1 proj5: 5 input projections -> fragment-layout bf16 intermediates in ws
//   (grid 5120, 256 thr, 128-reg cap, 32KB LDS, 4 blocks/CU)
// K2 attn_out: attention + 3 PV + 3 out-projections, fragments loaded
//   directly from ws (no staging/projT in-kernel -> ~115 regs, 32KB LDS,
//   2 blocks/CU, 16 waves/CU)
// Fallback: verified R7 fused kernel if ws_size < 169 MB.
// ---------------------------------------------------------------------------

typedef __attribute__((ext_vector_type(8))) __bf16 bf16x8;
typedef __attribute__((ext_vector_type(4))) float f32x4;
typedef __attribute__((ext_vector_type(4))) unsigned short u16x4;

__device__ __forceinline__ unsigned short f2bf(float f) {
  return __builtin_bit_cast(unsigned short, (__bf16)f);
}
__device__ __forceinline__ unsigned pk2(float lo, float hi) {
  return (unsigned)f2bf(lo) | ((unsigned)f2bf(hi) << 16);
}
__device__ __forceinline__ int swz256(int row, int col) {   // 256-elem (512B) rows
  return row * 256 + (col ^ ((row & 31) << 3));
}
__device__ __forceinline__ f32x4 mfma16(bf16x8 a, bf16x8 b, f32x4 c) {
  return __builtin_amdgcn_mfma_f32_16x16x32_bf16(a, b, c, 0, 0, 0);
}

// ---------------- pre-kernel 1: pack weights into fragment layout -----------
__global__ void pack_weights(const float* __restrict__ W0, const float* __restrict__ W1,
                             const float* __restrict__ W2, const float* __restrict__ W3,
                             const float* __restrict__ W4, const float* __restrict__ W5,
                             const float* __restrict__ W6, const float* __restrict__ W7,
                             unsigned short* __restrict__ pk) {
  int t = blockIdx.x * 256 + threadIdx.x;   // 65536 threads
  int mat = t >> 13;
  int w   = (t >> 11) & 3;
  int blk = (t >> 9) & 3;
  int kc  = (t >> 6) & 7;
  int l   = t & 63;
  const float* W = (mat == 0) ? W0 : (mat == 1) ? W1 : (mat == 2) ? W2 : (mat == 3) ? W3
                 : (mat == 4) ? W4 : (mat == 5) ? W5 : (mat == 6) ? W6 : W7;
  const float* src = W + (64 * w + 16 * blk + (l & 15)) * 256 + 32 * kc + 8 * (l >> 4);
  unsigned short* dst = pk + (size_t)t * 8;
#pragma unroll
  for (int i = 0; i < 8; ++i) dst[i] = f2bf(src[i]);
}

// ---------------- pre-kernel 2: bmt[wi][h][qb][t][lane][r] ------------------
__global__ void make_bmt(const float* __restrict__ mask, const float* __restrict__ btab,
                         const int* __restrict__ ridx, float* __restrict__ bmt) {
  int t = blockIdx.x * 256 + threadIdx.x;   // 2,097,152 threads
  int r  = t & 3;
  int l  = (t >> 2) & 63;
  int mf = (t >> 8) & 3;
  int nf = (t >> 10) & 3;
  int h  = (t >> 12) & 7;
  int wi = t >> 15;
  int q = 16 * nf + (l & 15);
  int k = 16 * mf + 4 * (l >> 4) + r;
  bmt[t] = mask[(wi * 64 + q) * 64 + k] + btab[ridx[q * 64 + k] * 8 + h];
}

// ---------------- butterfly: two 16-row C-layout blocks -> one frag ---------
__device__ __forceinline__ bf16x8 butterfly(f32x4 C0, f32x4 C1, int c4, int r16) {
  unsigned a0 = pk2(C0[0], C0[1]), a1 = pk2(C0[2], C0[3]);
  unsigned b0 = pk2(C1[0], C1[1]), b1 = pk2(C1[2], C1[3]);
  int src0 = (((2 * c4) & 3) << 4) + r16;
  int src1 = (((2 * c4 + 1) & 3) << 4) + r16;
  unsigned A0 = (unsigned)__shfl((int)a0, src0);
  unsigned A1 = (unsigned)__shfl((int)a1, src0);
  unsigned A2 = (unsigned)__shfl((int)a0, src1);
  unsigned A3 = (unsigned)__shfl((int)a1, src1);
  unsigned B0 = (unsigned)__shfl((int)b0, src0);
  unsigned B1 = (unsigned)__shfl((int)b1, src0);
  unsigned B2 = (unsigned)__shfl((int)b0, src1);
  unsigned B3 = (unsigned)__shfl((int)b1, src1);
  bool hi = c4 >= 2;
  union { unsigned u[4]; bf16x8 v; } r;
  r.u[0] = hi ? B0 : A0;
  r.u[1] = hi ? B1 : A1;
  r.u[2] = hi ? B2 : A2;
  r.u[3] = hi ? B3 : A3;
  return r.v;
}

// ---------------- staging (256 threads): half-tile chunks (32 regs) ---------
__device__ __forceinline__ void load8(f32x4 r[8], const float* __restrict__ X,
                                      int b, int tid, int half) {
  const f32x4* src = reinterpret_cast<const f32x4*>(X + (size_t)b * 16384) + half * 2048;
#pragma unroll
  for (int it = 0; it < 8; ++it) r[it] = src[it * 256 + tid];
}
__device__ __forceinline__ void write8(unsigned short* T, const f32x4 r[8], int tid, int half) {
#pragma unroll
  for (int it = 0; it < 8; ++it) {
    int f = half * 2048 + it * 256 + tid;
    int row = f >> 6;
    int col = (f & 63) << 2;
    u16x4 p;
    p[0] = f2bf(r[it][0]); p[1] = f2bf(r[it][1]);
    p[2] = f2bf(r[it][2]); p[3] = f2bf(r[it][3]);
    *reinterpret_cast<u16x4*>(T + swz256(row, col)) = p;
  }
}
__device__ __forceinline__ void stage_tile(unsigned short* T, const float* __restrict__ X,
                                           int b, int tid) {
  f32x4 r[8];
  load8(r, X, b, tid, 0);
  write8(T, r, tid, 0);
  load8(r, X, b, tid, 1);
  write8(T, r, tid, 1);
}

// per-wave packed-weight base: rows [64*w2, 64*w2+64) of mat
__device__ __forceinline__ const unsigned short* pwBase7(const unsigned short* pk,
                                                         int mat, int w2) {
  return pk + mat * 65536 + w2 * 16384;
}

// ---------------- transposed proj (2 heads): M = W X^T -> frags -------------
__device__ __forceinline__ void projT2(const unsigned short* __restrict__ T,
                                       const unsigned short* __restrict__ pw,
                                       const float* __restrict__ bias, float scale,
                                       int lane, int w2, bf16x8 fA[4], bf16x8 fB[4]) {
  const int r16 = lane & 15, c4 = lane >> 4;
  f32x4 z = {0.f, 0.f, 0.f, 0.f};
  f32x4 acc[4][4];
#pragma unroll
  for (int j = 0; j < 4; ++j)
#pragma unroll
    for (int nf = 0; nf < 4; ++nf) acc[j][nf] = z;
#pragma unroll
  for (int kc = 0; kc < 8; ++kc) {
    bf16x8 aw[4], bx[4];
#pragma unroll
    for (int j = 0; j < 4; ++j)
      aw[j] = *reinterpret_cast<const bf16x8*>(pw + (j * 8 + kc) * 512 + lane * 8);
#pragma unroll
    for (int nf = 0; nf < 4; ++nf)
      bx[nf] = *reinterpret_cast<const bf16x8*>(T + swz256(16 * nf + r16, 32 * kc + 8 * c4));
#pragma unroll
    for (int j = 0; j < 4; ++j)
#pragma unroll
      for (int nf = 0; nf < 4; ++nf) acc[j][nf] = mfma16(aw[j], bx[nf], acc[j][nf]);
  }
#pragma unroll
  for (int j = 0; j < 4; ++j) {
    f32x4 b4 = *reinterpret_cast<const f32x4*>(bias + 64 * w2 + 16 * j + 4 * c4);
#pragma unroll
    for (int nf = 0; nf < 4; ++nf)
#pragma unroll
      for (int r = 0; r < 4; ++r) acc[j][nf][r] = (acc[j][nf][r] + b4[r]) * scale;
  }
#pragma unroll
  for (int nf = 0; nf < 4; ++nf) {
    fA[nf] = butterfly(acc[0][nf], acc[1][nf], c4, r16);
    fB[nf] = butterfly(acc[2][nf], acc[3][nf], c4, r16);
  }
}

// ---------------- attention (one head), all-register ------------------------
__device__ __forceinline__ void attn_head(const bf16x8 Qf[4], const bf16x8 Kf[4],
                                          const float* __restrict__ bmb,
                                          int lane, bf16x8 Pf[4][2]) {
  const int r16 = lane & 15, c4 = lane >> 4;
  f32x4 z = {0.f, 0.f, 0.f, 0.f};
#pragma unroll
  for (int qb = 0; qb < 4; ++qb) {
    f32x4 s[4];
#pragma unroll
    for (int t = 0; t < 4; ++t) s[t] = mfma16(Kf[t], Qf[qb], z);
    float mx = -1e30f;
#pragma unroll
    for (int t = 0; t < 4; ++t) {
      f32x4 bm4 = *reinterpret_cast<const f32x4*>(bmb + (((qb * 4 + t) * 64 + lane) << 2));
#pragma unroll
      for (int r = 0; r < 4; ++r) {
        s[t][r] += bm4[r];
        mx = fmaxf(mx, s[t][r]);
      }
    }
    mx = fmaxf(mx, __shfl_xor(mx, 16));
    mx = fmaxf(mx, __shfl_xor(mx, 32));
    float sum = 0.f;
#pragma unroll
    for (int t = 0; t < 4; ++t)
#pragma unroll
      for (int r = 0; r < 4; ++r) {
        s[t][r] = __expf(s[t][r] - mx);
        sum += s[t][r];
      }
    sum += __shfl_xor(sum, 16);
    sum += __shfl_xor(sum, 32);
    float inv = 1.0f / sum;
#pragma unroll
    for (int kc = 0; kc < 2; ++kc) {
      f32x4 p0, p1;
#pragma unroll
      for (int r = 0; r < 4; ++r) {
        p0[r] = s[2 * kc][r] * inv;
        p1[r] = s[2 * kc + 1][r] * inv;
      }
      Pf[qb][kc] = butterfly(p0, p1, c4, r16);
    }
  }
}

// ---------------- normal proj (64 cols/wave) --------------------------------
__device__ __forceinline__ void projN64(const unsigned short* __restrict__ T,
                                        const unsigned short* __restrict__ pw,
                                        int lane, f32x4 acc[4][4]) {
  const int r16 = lane & 15, c4 = lane >> 4;
  f32x4 z = {0.f, 0.f, 0.f, 0.f};
#pragma unroll
  for (int mf = 0; mf < 4; ++mf)
#pragma unroll
    for (int nf = 0; nf < 4; ++nf) acc[mf][nf] = z;
#pragma unroll
  for (int kc = 0; kc < 8; ++kc) {
    bf16x8 a[4], bb[4];
#pragma unroll
    for (int mf = 0; mf < 4; ++mf)
      a[mf] = *reinterpret_cast<const bf16x8*>(T + swz256(16 * mf + r16, 32 * kc + 8 * c4));
#pragma unroll
    for (int nf = 0; nf < 4; ++nf)
      bb[nf] = *reinterpret_cast<const bf16x8*>(pw + (nf * 8 + kc) * 512 + lane * 8);
#pragma unroll
    for (int mf = 0; mf < 4; ++mf)
#pragma unroll
      for (int nf = 0; nf < 4; ++nf) acc[mf][nf] = mfma16(a[mf], bb[nf], acc[mf][nf]);
  }
}

// V epilogue (2 heads): add per-col bias, butterfly -> PV B-frags
__device__ __forceinline__ void vFrag2(f32x4 acc[4][4], const float* __restrict__ bias,
                                       int lane, int w2, bf16x8 VfA[2][2], bf16x8 VfB[2][2]) {
  const int r16 = lane & 15, c4 = lane >> 4;
#pragma unroll
  for (int nf = 0; nf < 4; ++nf) {
    float bb = bias[64 * w2 + 16 * nf + r16];
#pragma unroll
    for (int mf = 0; mf < 4; ++mf)
#pragma unroll
      for (int r = 0; r < 4; ++r) acc[mf][nf][r] += bb;
  }
#pragma unroll
  for (int nf = 0; nf < 2; ++nf) {
    VfA[0][nf] = butterfly(acc[0][nf], acc[1][nf], c4, r16);
    VfA[1][nf] = butterfly(acc[2][nf], acc[3][nf], c4, r16);
    VfB[0][nf] = butterfly(acc[0][nf + 2], acc[1][nf + 2], c4, r16);
    VfB[1][nf] = butterfly(acc[2][nf + 2], acc[3][nf + 2], c4, r16);
  }
}

// PV: O = P V for one head -> O tile cols [32h, 32h+32)
__device__ __forceinline__ void pv_store(const bf16x8 Pf[4][2], const bf16x8 Vf[2][2],
                                         unsigned short* OS, int lane, int h) {
  const int r16 = lane & 15, c4 = lane >> 4;
  f32x4 z = {0.f, 0.f, 0.f, 0.f};
  f32x4 o[4][2];
#pragma unroll
  for (int qb = 0; qb < 4; ++qb)
#pragma unroll
    for (int nf = 0; nf < 2; ++nf) o[qb][nf] = z;
#pragma unroll
  for (int kc = 0; kc < 2; ++kc)
#pragma unroll
    for (int qb = 0; qb < 4; ++qb)
#pragma unroll
      for (int nf = 0; nf < 2; ++nf)
        o[qb][nf] = mfma16(Pf[qb][kc], Vf[kc][nf], o[qb][nf]);
#pragma unroll
  for (int qb = 0; qb < 4; ++qb)
#pragma unroll
    for (int nf = 0; nf < 2; ++nf)
#pragma unroll
      for (int r = 0; r < 4; ++r)
        OS[swz256(16 * qb + 4 * c4 + r, 32 * h + 16 * nf + r16)] = f2bf(o[qb][nf][r]);
}

// ---------------- normal proj (32 cols/wave) + out store --------------------
__device__ __forceinline__ void projN32(const unsigned short* __restrict__ T,
                                        const unsigned short* __restrict__ pw,
                                        int lane, f32x4 acc[4][2]) {
  const int r16 = lane & 15, c4 = lane >> 4;
  f32x4 z = {0.f, 0.f, 0.f, 0.f};
#pragma unroll
  for (int mf = 0; mf < 4; ++mf)
#pragma unroll
    for (int nf = 0; nf < 2; ++nf) acc[mf][nf] = z;
#pragma unroll
  for (int kc = 0; kc < 8; ++kc) {
    bf16x8 a[4], bb[2];
#pragma unroll
    for (int mf = 0; mf < 4; ++mf)
      a[mf] = *reinterpret_cast<const bf16x8*>(T + swz256(16 * mf + r16, 32 * kc + 8 * c4));
#pragma unroll
    for (int nf = 0; nf < 2; ++nf)
      bb[nf] = *reinterpret_cast<const bf16x8*>(pw + nf * 4096 + kc * 512 + lane * 8);
#pragma unroll
    for (int mf = 0; mf < 4; ++mf)
#pragma unroll
      for (int nf = 0; nf < 2; ++nf) acc[mf][nf] = mfma16(a[mf], bb[nf], acc[mf][nf]);
  }
}
__device__ __forceinline__ void outProj(const unsigned short* __restrict__ OS,
                                        const unsigned short* __restrict__ pw,
                                        const float* __restrict__ bias,
                                        float* __restrict__ dst, int lane, int w) {
  const int r16 = lane & 15, c4 = lane >> 4;
  f32x4 acc[4][2];
  projN32(OS, pw, lane, acc);
#pragma unroll
  for (int nf = 0; nf < 2; ++nf) {
    float bb = bias[32 * w + 16 * nf + r16];
#pragma unroll
    for (int mf = 0; mf < 4; ++mf)
#pragma unroll
      for (int r = 0; r < 4; ++r)
        dst[(16 * mf + 4 * c4 + r) * 256 + 32 * w + 16 * nf + r16] = acc[mf][nf][r] + bb;
  }
}

// out-proj 64 cols/wave (fallback kernel)
__device__ __forceinline__ void outProj64(const unsigned short* __restrict__ OS,
                                          const unsigned short* __restrict__ pw,
                                          const float* __restrict__ bias,
                                          float* __restrict__ dst, int lane, int w2) {
  const int r16 = lane & 15, c4 = lane >> 4;
  f32x4 acc[4][4];
  projN64(OS, pw, lane, acc);
#pragma unroll
  for (int nf = 0; nf < 4; ++nf) {
    float bb = bias[64 * w2 + 16 * nf + r16];
#pragma unroll
    for (int mf = 0; mf < 4; ++mf)
#pragma unroll
      for (int r = 0; r < 4; ++r)
        dst[(16 * mf + 4 * c4 + r) * 256 + 64 * w2 + 16 * nf + r16] = acc[mf][nf][r] + bb;
  }
}

// ===================== K1: proj5 — 5 projections to fragments ===============
// bid = mat*1024 + win. mat 0:q->qf, 1:k->kf, 2:v 3:sc 4:sh -> vf.
__global__ __launch_bounds__(256, 4) void proj5(
    const float* __restrict__ gq, const float* __restrict__ gk,
    const float* __restrict__ gv, const float* __restrict__ gsc,
    const float* __restrict__ gsh, const unsigned short* __restrict__ pk,
    const float* __restrict__ b_q, const float* __restrict__ b_k,
    const float* __restrict__ b_v, const float* __restrict__ b_vs,
    const float* __restrict__ b_vh,
    unsigned short* __restrict__ qf, unsigned short* __restrict__ kf,
    unsigned short* __restrict__ vf) {
  __shared__ __align__(16) unsigned short XS[16384];   // 32 KiB
  const int bid = blockIdx.x;
  const int mat = bid >> 10;
  const int win = bid & 1023;
  const int tid = threadIdx.x;
  const int lane = tid & 63;
  const int w2 = tid >> 6;
  const float* X = (mat == 0) ? gq : (mat == 1) ? gk : (mat == 2) ? gv
                 : (mat == 3) ? gsc : gsh;
  stage_tile(XS, X, win, tid);
  __syncthreads();
  if (mat < 2) {
    bf16x8 fA[4], fB[4];
    projT2(XS, pwBase7(pk, mat, w2), mat == 0 ? b_q : b_k,
           mat == 0 ? 0.17677669529663687f : 1.0f, lane, w2, fA, fB);
    unsigned short* dst = (mat == 0 ? qf : kf) + (size_t)win * 16384 + lane * 8;
#pragma unroll
    for (int nf = 0; nf < 4; ++nf) {
      *reinterpret_cast<bf16x8*>(dst + (2 * w2) * 2048 + nf * 512) = fA[nf];
      *reinterpret_cast<bf16x8*>(dst + (2 * w2 + 1) * 2048 + nf * 512) = fB[nf];
    }
  } else {
    f32x4 acc[4][4];
    projN64(XS, pwBase7(pk, mat, w2), lane, acc);
    bf16x8 VfA[2][2], VfB[2][2];
    vFrag2(acc, mat == 2 ? b_v : (mat == 3 ? b_vs : b_vh), lane, w2, VfA, VfB);
    unsigned short* dst = vf + (size_t)(mat - 2) * 16777216 + (size_t)win * 16384 + lane * 8;
#pragma unroll
    for (int kc = 0; kc < 2; ++kc)
#pragma unroll
      for (int nf = 0; nf < 2; ++nf) {
        *reinterpret_cast<bf16x8*>(dst + (2 * w2) * 2048 + (kc * 2 + nf) * 512) = VfA[kc][nf];
        *reinterpret_cast<bf16x8*>(dst + (2 * w2 + 1) * 2048 + (kc * 2 + nf) * 512) = VfB[kc][nf];
      }
  }
}

// ===================== K2: attn_out — attention + 3 out-projections =========
__global__ __launch_bounds__(512, 4) void attn_out(
    const unsigned short* __restrict__ qf, const unsigned short* __restrict__ kf,
    const unsigned short* __restrict__ vf, const unsigned short* __restrict__ pk,
    const float* __restrict__ b_px, const float* __restrict__ b_ps,
    const float* __restrict__ b_ph, const float* __restrict__ bmt,
    float* __restrict__ out) {
  __shared__ __align__(16) unsigned short OS[16384];   // 32 KiB O tile
  const int b = blockIdx.x;
  const int tid = threadIdx.x;
  const int lane = tid & 63;
  const int w = tid >> 6;                 // wave id == head id
  const int wi = b & 63;
  const size_t fb = (size_t)b * 16384 + w * 2048 + lane * 8;

  bf16x8 Qf[4], Kf[4], Pf[4][2], VfA[2][2], VfB[2][2];
#pragma unroll
  for (int nf = 0; nf < 4; ++nf) {
    Qf[nf] = *reinterpret_cast<const bf16x8*>(qf + fb + nf * 512);
    Kf[nf] = *reinterpret_cast<const bf16x8*>(kf + fb + nf * 512);
  }
#pragma unroll
  for (int kc = 0; kc < 2; ++kc)
#pragma unroll
    for (int nf = 0; nf < 2; ++nf)
      VfA[kc][nf] = *reinterpret_cast<const bf16x8*>(vf + fb + (kc * 2 + nf) * 512);

  attn_head(Qf, Kf, bmt + ((size_t)(wi * 8 + w) << 12), lane, Pf);

  // ---- output 0 (x) ----
  pv_store(Pf, VfA, OS, lane, w);
  __syncthreads();
#pragma unroll
  for (int kc = 0; kc < 2; ++kc)
#pragma unroll
    for (int nf = 0; nf < 2; ++nf)
      VfB[kc][nf] = *reinterpret_cast<const bf16x8*>(vf + 16777216 + fb + (kc * 2 + nf) * 512);
  outProj(OS, pk + 5 * 65536 + w * 8192, b_px, out + (size_t)b * 16384, lane, w);
  __syncthreads();

  // ---- output 1 (scale) ----
  pv_store(Pf, VfB, OS, lane, w);
  __syncthreads();
#pragma unroll
  for (int kc = 0; kc < 2; ++kc)
#pragma unroll
    for (int nf = 0; nf < 2; ++nf)
      VfA[kc][nf] = *reinterpret_cast<const bf16x8*>(vf + 2 * 16777216 + fb + (kc * 2 + nf) * 512);
  outProj(OS, pk + 6 * 65536 + w * 8192, b_ps, out + 16777216 + (size_t)b * 16384, lane, w);
  __syncthreads();

  // ---- output 2 (shift) ----
  pv_store(Pf, VfA, OS, lane, w);
  __syncthreads();
  outProj(OS, pk + 7 * 65536 + w * 8192, b_ph, out + 33554432 + (size_t)b * 16384, lane, w);
}

// ===================== Fallback: R7 fused kernel (verified, 260us) ==========
__global__ __launch_bounds__(256, 2) void win_attn_fused(
    const float* __restrict__ gq, const float* __restrict__ gk, const float* __restrict__ gv,
    const float* __restrict__ gsc, const float* __restrict__ gsh,
    const unsigned short* __restrict__ pk,
    const float* __restrict__ b_q, const float* __restrict__ b_k, const float* __restrict__ b_v,
    const float* __restrict__ b_vs, const float* __restrict__ b_vh,
    const float* __restrict__ b_px, const float* __restrict__ b_ps, const float* __restrict__ b_ph,
    const float* __restrict__ bmt, float* __restrict__ out) {
  __shared__ __align__(16) unsigned short sm[32768];
  unsigned short* XS = sm;
  unsigned short* OS = sm + 16384;
  const int b = blockIdx.x;
  const int tid = threadIdx.x;
  const int lane = tid & 63;
  const int w2 = tid >> 6;
  const int wi = b & 63;
  bf16x8 PfA[4][2], PfB[4][2];
  stage_tile(XS, gq, b, tid);
  stage_tile(OS, gk, b, tid);
  __syncthreads();
  {
    bf16x8 QfA[4], QfB[4], KfA[4], KfB[4];
    projT2(XS, pwBase7(pk, 0, w2), b_q, 0.17677669529663687f, lane, w2, QfA, QfB);
    __syncthreads();
    projT2(OS, pwBase7(pk, 1, w2), b_k, 1.0f, lane, w2, KfA, KfB);
    attn_head(QfA, KfA, bmt + ((size_t)(wi * 8 + 2 * w2) << 12), lane, PfA);
    attn_head(QfB, KfB, bmt + ((size_t)(wi * 8 + 2 * w2 + 1) << 12), lane, PfB);
    stage_tile(XS, gv, b, tid);
  }
  __syncthreads();
  {
    f32x4 acc[4][4];
    projN64(XS, pwBase7(pk, 2, w2), lane, acc);
    bf16x8 VfA[2][2], VfB[2][2];
    vFrag2(acc, b_v, lane, w2, VfA, VfB);
    pv_store(PfA, VfA, OS, lane, 2 * w2);
    pv_store(PfB, VfB, OS, lane, 2 * w2 + 1);
  }
  __syncthreads();
  outProj64(OS, pwBase7(pk, 5, w2), b_px, out + (size_t)b * 16384, lane, w2);
  stage_tile(XS, gsc, b, tid);
  __syncthreads();
  {
    f32x4 acc[4][4];
    projN64(XS, pwBase7(pk, 3, w2), lane, acc);
    bf16x8 VfA[2][2], VfB[2][2];
    vFrag2(acc, b_vs, lane, w2, VfA, VfB);
    pv_store(PfA, VfA, OS, lane, 2 * w2);
    pv_store(PfB, VfB, OS, lane, 2 * w2 + 1);
  }
  __syncthreads();
  outProj64(OS, pwBase7(pk, 6, w2), b_ps, out + 16777216 + (size_t)b * 16384, lane, w2);
  stage_tile(XS, gsh, b, tid);
  __syncthreads();
  {
    f32x4 acc[4][4];
    projN64(XS, pwBase7(pk, 4, w2), lane, acc);
    bf16x8 VfA[2][2], VfB[2][2];
    vFrag2(acc, b_vh, lane, w2, VfA, VfB);
    pv_store(PfA, VfA, OS, lane, 2 * w2);
    pv_store(PfB, VfB, OS, lane, 2 * w2 + 1);
  }
  __syncthreads();
  outProj64(OS, pwBase7(pk, 7, w2), b_ph, out + 33554432 + (size_t)b * 16384, lane, w2);
}

// ---------------------------------------------------------------------------
extern "C" void kernel_launch(void* const* d_in, const int* in_sizes, int n_in,
                              void* d_out, int out_size, void* d_ws, size_t ws_size,
                              hipStream_t stream) {
  const float* Xq   = (const float*)d_in[0];
  const float* Xk   = (const float*)d_in[1];
  const float* Xv   = (const float*)d_in[2];
  const float* Xsc  = (const float*)d_in[3];
  const float* Xsh  = (const float*)d_in[4];
  const float* mask = (const float*)d_in[5];
  const float* Wq   = (const float*)d_in[6];  const float* bq  = (const float*)d_in[7];
  const float* Wk   = (const float*)d_in[8];  const float* bk  = (const float*)d_in[9];
  const float* Wv   = (const float*)d_in[10]; const float* bv  = (const float*)d_in[11];
  const float* Wvs  = (const float*)d_in[12]; const float* bvs = (const float*)d_in[13];
  const float* Wvh  = (const float*)d_in[14]; const float* bvh = (const float*)d_in[15];
  const float* Wpx  = (const float*)d_in[16]; const float* bpx = (const float*)d_in[17];
  const float* Wps  = (const float*)d_in[18]; const float* bps = (const float*)d_in[19];
  const float* Wph  = (const float*)d_in[20]; const float* bph = (const float*)d_in[21];
  const float* btab = (const float*)d_in[22];
  const int*   ridx = (const int*)d_in[23];

  char* ws = (char*)d_ws;
  unsigned short* pk = (unsigned short*)ws;                    // 1 MB
  float* bmt = (float*)(ws + (size_t)1048576);                 // 8 MB
  unsigned short* qf = (unsigned short*)(ws + (size_t)9437184);        // 32 MB
  unsigned short* kf = (unsigned short*)(ws + (size_t)9437184 + 33554432);   // 32 MB
  unsigned short* vf = (unsigned short*)(ws + (size_t)9437184 + 67108864);   // 96 MB
  const size_t need = (size_t)9437184 + 67108864 + 100663296;  // 169 MB

  pack_weights<<<256, 256, 0, stream>>>(Wq, Wk, Wv, Wvs, Wvh, Wpx, Wps, Wph, pk);
  make_bmt<<<8192, 256, 0, stream>>>(mask, btab, ridx, bmt);

  if (ws_size >= need) {
    proj5<<<5120, 256, 0, stream>>>(Xq, Xk, Xv, Xsc, Xsh, pk,
                                    bq, bk, bv, bvs, bvh, qf, kf, vf);
    attn_out<<<1024, 512, 0, stream>>>(qf, kf, vf, pk, bpx, bps, bph,
                                       bmt, (float*)d_out);
  } else {
    win_attn_fused<<<1024, 256, 0, stream>>>(Xq, Xk, Xv, Xsc, Xsh, pk,
                                             bq, bk, bv, bvs, bvh, bpx, bps, bph,
                                             bmt, (float*)d_out);
  }
}

// Round 10
// 240.165 us; speedup vs baseline: 1.3271x; 1.3271x over previous
//
#include <hip/hip_runtime.h>

// ---------------------------------------------------------------------------
// WindowAttention fused kernel for MI355X (gfx950) — R9
// B=1024 windows, N=64 tokens, C=256, H=8 heads, hd=32
// R4 schedule + global_load_lds async staging: inputs land in LDS as raw
// fp32 (A/B 64KB tiles, swizzled via pre-swizzled per-lane global address),
// issued one phase ahead of use; fragments convert fp32->bf16 at read.
// OS = 32KB bf16 O-tile. LDS=160KB, 512 thr / 8 waves / 1 head per wave,
// launch_bounds(512,2) (256-reg cap, the only no-spill config, proven R4).
// ---------------------------------------------------------------------------

typedef __attribute__((ext_vector_type(8))) __bf16 bf16x8;
typedef __attribute__((ext_vector_type(4))) float f32x4;

__device__ __forceinline__ unsigned short f2bf(float f) {
  return __builtin_bit_cast(unsigned short, (__bf16)f);
}
__device__ __forceinline__ unsigned pk2(float lo, float hi) {
  return (unsigned)f2bf(lo) | ((unsigned)f2bf(hi) << 16);
}
__device__ __forceinline__ int swz256(int row, int col) {   // bf16 OS tile swizzle
  return row * 256 + (col ^ ((row & 31) << 3));
}
__device__ __forceinline__ f32x4 mfma16(bf16x8 a, bf16x8 b, f32x4 c) {
  return __builtin_amdgcn_mfma_f32_16x16x32_bf16(a, b, c, 0, 0, 0);
}

// ---------------- pre-kernel 1: pack weights into fragment layout -----------
// pk[mat][w64][blk][kc][lane][i] = W[64*w64+16*blk+(l&15)][32*kc+8*(l>>4)+i]
__global__ void pack_weights(const float* __restrict__ W0, const float* __restrict__ W1,
                             const float* __restrict__ W2, const float* __restrict__ W3,
                             const float* __restrict__ W4, const float* __restrict__ W5,
                             const float* __restrict__ W6, const float* __restrict__ W7,
                             unsigned short* __restrict__ pk) {
  int t = blockIdx.x * 256 + threadIdx.x;   // 65536 threads
  int mat = t >> 13;
  int w   = (t >> 11) & 3;
  int blk = (t >> 9) & 3;
  int kc  = (t >> 6) & 7;
  int l   = t & 63;
  const float* W = (mat == 0) ? W0 : (mat == 1) ? W1 : (mat == 2) ? W2 : (mat == 3) ? W3
                 : (mat == 4) ? W4 : (mat == 5) ? W5 : (mat == 6) ? W6 : W7;
  const float* src = W + (64 * w + 16 * blk + (l & 15)) * 256 + 32 * kc + 8 * (l >> 4);
  unsigned short* dst = pk + (size_t)t * 8;
#pragma unroll
  for (int i = 0; i < 8; ++i) dst[i] = f2bf(src[i]);
}

// ---------------- pre-kernel 2: bmt[wi][h][qb][t][lane][r] ------------------
__global__ void make_bmt(const float* __restrict__ mask, const float* __restrict__ btab,
                         const int* __restrict__ ridx, float* __restrict__ bmt) {
  int t = blockIdx.x * 256 + threadIdx.x;   // 2,097,152 threads
  int r  = t & 3;
  int l  = (t >> 2) & 63;
  int mf = (t >> 8) & 3;
  int nf = (t >> 10) & 3;
  int h  = (t >> 12) & 7;
  int wi = t >> 15;
  int q = 16 * nf + (l & 15);
  int k = 16 * mf + 4 * (l >> 4) + r;
  bmt[t] = mask[(wi * 64 + q) * 64 + k] + btab[ridx[q * 64 + k] * 8 + h];
}

// ---------------- butterfly: two 16-row C-layout blocks -> one frag ---------
__device__ __forceinline__ bf16x8 butterfly(f32x4 C0, f32x4 C1, int c4, int r16) {
  unsigned a0 = pk2(C0[0], C0[1]), a1 = pk2(C0[2], C0[3]);
  unsigned b0 = pk2(C1[0], C1[1]), b1 = pk2(C1[2], C1[3]);
  int src0 = (((2 * c4) & 3) << 4) + r16;
  int src1 = (((2 * c4 + 1) & 3) << 4) + r16;
  unsigned A0 = (unsigned)__shfl((int)a0, src0);
  unsigned A1 = (unsigned)__shfl((int)a1, src0);
  unsigned A2 = (unsigned)__shfl((int)a0, src1);
  unsigned A3 = (unsigned)__shfl((int)a1, src1);
  unsigned B0 = (unsigned)__shfl((int)b0, src0);
  unsigned B1 = (unsigned)__shfl((int)b1, src0);
  unsigned B2 = (unsigned)__shfl((int)b0, src1);
  unsigned B3 = (unsigned)__shfl((int)b1, src1);
  bool hi = c4 >= 2;
  union { unsigned u[4]; bf16x8 v; } r;
  r.u[0] = hi ? B0 : A0;
  r.u[1] = hi ? B1 : A1;
  r.u[2] = hi ? B2 : A2;
  r.u[3] = hi ? B3 : A3;
  return r.v;
}

// ---------------- async staging: global_load_lds, pre-swizzled source -------
// Wave w fills rows r = 8w..8w+7; lane l loads global chunk (r, l^(r&15))
// into LDS chunk (r, l)  =>  X[r][chunk c] lives at LDS chunk (r, c^(r&15)).
__device__ __forceinline__ void issue_tile(const float* __restrict__ X, int b,
                                           float* Tlds, int w, int lane) {
#pragma unroll
  for (int i = 0; i < 8; ++i) {
    int r = w * 8 + i;
    const float* src = X + (size_t)b * 16384 + r * 256 + ((lane ^ (r & 15)) << 2);
    __builtin_amdgcn_global_load_lds(
        (const __attribute__((address_space(1))) unsigned int*)src,
        (__attribute__((address_space(3))) unsigned int*)(Tlds + r * 256),
        16, 0, 0);
  }
}

// read one bf16x8 fragment (8 consecutive floats of X[row]) from fp32 tile
__device__ __forceinline__ bf16x8 ldsFragF32(const float* __restrict__ T,
                                             int row, int col4) {
  const f32x4* T4 = reinterpret_cast<const f32x4*>(T);
  int base = row * 64;
  int m = row & 15;
  f32x4 x0 = T4[base + (col4 ^ m)];
  f32x4 x1 = T4[base + ((col4 + 1) ^ m)];
  union { unsigned u[4]; bf16x8 v; } r;
  r.u[0] = pk2(x0[0], x0[1]);
  r.u[1] = pk2(x0[2], x0[3]);
  r.u[2] = pk2(x1[0], x1[1]);
  r.u[3] = pk2(x1[2], x1[3]);
  return r.v;
}

// per-head packed-weight base: rows [32w, 32w+32) of mat
__device__ __forceinline__ const unsigned short* pwBase(const unsigned short* pk,
                                                        int mat, int w) {
  return pk + mat * 65536 + (w >> 1) * 16384 + (w & 1) * 8192;
}

// ---------------- transposed proj (one head) from fp32 tile -----------------
// frag[nf]: lane holds M[d=8c4+i][tok=16nf+r16]  (M = W X^T + bias, *scale)
__device__ __forceinline__ void projT_head_f32(const float* __restrict__ T,
                                               const unsigned short* __restrict__ pw,
                                               const float* __restrict__ bias, float scale,
                                               int lane, int w, bf16x8 frag[4]) {
  const int r16 = lane & 15, c4 = lane >> 4;
  f32x4 z = {0.f, 0.f, 0.f, 0.f};
  f32x4 acc[2][4];
#pragma unroll
  for (int j = 0; j < 2; ++j)
#pragma unroll
    for (int nf = 0; nf < 4; ++nf) acc[j][nf] = z;
#pragma unroll
  for (int kc = 0; kc < 8; ++kc) {
    bf16x8 aw[2], bx[4];
#pragma unroll
    for (int j = 0; j < 2; ++j)
      aw[j] = *reinterpret_cast<const bf16x8*>(pw + j * 4096 + kc * 512 + lane * 8);
#pragma unroll
    for (int nf = 0; nf < 4; ++nf)
      bx[nf] = ldsFragF32(T, 16 * nf + r16, 8 * kc + 2 * c4);
#pragma unroll
    for (int j = 0; j < 2; ++j)
#pragma unroll
      for (int nf = 0; nf < 4; ++nf) acc[j][nf] = mfma16(aw[j], bx[nf], acc[j][nf]);
  }
#pragma unroll
  for (int j = 0; j < 2; ++j) {
    f32x4 b4 = *reinterpret_cast<const f32x4*>(bias + 32 * w + 16 * j + 4 * c4);
#pragma unroll
    for (int nf = 0; nf < 4; ++nf)
#pragma unroll
      for (int r = 0; r < 4; ++r) acc[j][nf][r] = (acc[j][nf][r] + b4[r]) * scale;
  }
#pragma unroll
  for (int nf = 0; nf < 4; ++nf)
    frag[nf] = butterfly(acc[0][nf], acc[1][nf], c4, r16);
}

// ---------------- attention (one head), all-register ------------------------
__device__ __forceinline__ void attn_head(const bf16x8 Qf[4], const bf16x8 Kf[4],
                                          const float* __restrict__ bmb,
                                          int lane, bf16x8 Pf[4][2]) {
  const int r16 = lane & 15, c4 = lane >> 4;
  f32x4 z = {0.f, 0.f, 0.f, 0.f};
#pragma unroll
  for (int qb = 0; qb < 4; ++qb) {
    f32x4 s[4];
#pragma unroll
    for (int t = 0; t < 4; ++t) s[t] = mfma16(Kf[t], Qf[qb], z);
    float mx = -1e30f;
#pragma unroll
    for (int t = 0; t < 4; ++t) {
      f32x4 bm4 = *reinterpret_cast<const f32x4*>(bmb + (((qb * 4 + t) * 64 + lane) << 2));
#pragma unroll
      for (int r = 0; r < 4; ++r) {
        s[t][r] += bm4[r];
        mx = fmaxf(mx, s[t][r]);
      }
    }
    mx = fmaxf(mx, __shfl_xor(mx, 16));
    mx = fmaxf(mx, __shfl_xor(mx, 32));
    float sum = 0.f;
#pragma unroll
    for (int t = 0; t < 4; ++t)
#pragma unroll
      for (int r = 0; r < 4; ++r) {
        s[t][r] = __expf(s[t][r] - mx);
        sum += s[t][r];
      }
    sum += __shfl_xor(sum, 16);
    sum += __shfl_xor(sum, 32);
    float inv = 1.0f / sum;
#pragma unroll
    for (int kc = 0; kc < 2; ++kc) {
      f32x4 p0, p1;
#pragma unroll
      for (int r = 0; r < 4; ++r) {
        p0[r] = s[2 * kc][r] * inv;
        p1[r] = s[2 * kc + 1][r] * inv;
      }
      Pf[qb][kc] = butterfly(p0, p1, c4, r16);
    }
  }
}

// ---------------- normal proj from fp32 tile (32 cols/wave) -----------------
__device__ __forceinline__ void projN32_f32(const float* __restrict__ T,
                                            const unsigned short* __restrict__ pw,
                                            int lane, f32x4 acc[4][2]) {
  const int r16 = lane & 15, c4 = lane >> 4;
  f32x4 z = {0.f, 0.f, 0.f, 0.f};
#pragma unroll
  for (int mf = 0; mf < 4; ++mf)
#pragma unroll
    for (int nf = 0; nf < 2; ++nf) acc[mf][nf] = z;
#pragma unroll
  for (int kc = 0; kc < 8; ++kc) {
    bf16x8 a[4], bb[2];
#pragma unroll
    for (int mf = 0; mf < 4; ++mf)
      a[mf] = ldsFragF32(T, 16 * mf + r16, 8 * kc + 2 * c4);
#pragma unroll
    for (int nf = 0; nf < 2; ++nf)
      bb[nf] = *reinterpret_cast<const bf16x8*>(pw + nf * 4096 + kc * 512 + lane * 8);
#pragma unroll
    for (int mf = 0; mf < 4; ++mf)
#pragma unroll
      for (int nf = 0; nf < 2; ++nf) acc[mf][nf] = mfma16(a[mf], bb[nf], acc[mf][nf]);
  }
}

// V epilogue: add per-col bias (d = 32w+16nf+r16), butterfly -> PV B-frags
__device__ __forceinline__ void vFrag(f32x4 acc[4][2], const float* __restrict__ bias,
                                      int lane, int w, bf16x8 Vf[2][2]) {
  const int r16 = lane & 15, c4 = lane >> 4;
#pragma unroll
  for (int nf = 0; nf < 2; ++nf) {
    float bb = bias[32 * w + 16 * nf + r16];
#pragma unroll
    for (int mf = 0; mf < 4; ++mf)
#pragma unroll
      for (int r = 0; r < 4; ++r) acc[mf][nf][r] += bb;
  }
#pragma unroll
  for (int nf = 0; nf < 2; ++nf) {
    Vf[0][nf] = butterfly(acc[0][nf], acc[1][nf], c4, r16);
    Vf[1][nf] = butterfly(acc[2][nf], acc[3][nf], c4, r16);
  }
}

// PV: O = P V for this head -> OS (bf16, swz256) cols [32w,32w+32)
__device__ __forceinline__ void pv_store(const bf16x8 Pf[4][2], const bf16x8 Vf[2][2],
                                         unsigned short* OS, int lane, int w) {
  const int r16 = lane & 15, c4 = lane >> 4;
  f32x4 z = {0.f, 0.f, 0.f, 0.f};
  f32x4 o[4][2];
#pragma unroll
  for (int qb = 0; qb < 4; ++qb)
#pragma unroll
    for (int nf = 0; nf < 2; ++nf) o[qb][nf] = z;
#pragma unroll
  for (int kc = 0; kc < 2; ++kc)
#pragma unroll
    for (int qb = 0; qb < 4; ++qb)
#pragma unroll
      for (int nf = 0; nf < 2; ++nf)
        o[qb][nf] = mfma16(Pf[qb][kc], Vf[kc][nf], o[qb][nf]);
#pragma unroll
  for (int qb = 0; qb < 4; ++qb)
#pragma unroll
    for (int nf = 0; nf < 2; ++nf)
#pragma unroll
      for (int r = 0; r < 4; ++r)
        OS[swz256(16 * qb + 4 * c4 + r, 32 * w + 16 * nf + r16)] = f2bf(o[qb][nf][r]);
}

// out-proj: bf16 OS tile @ W^T (32 cols/wave), add bias, store fp32 global
__device__ __forceinline__ void outProj(const unsigned short* __restrict__ OS,
                                        const unsigned short* __restrict__ pw,
                                        const float* __restrict__ bias,
                                        float* __restrict__ dst, int lane, int w) {
  const int r16 = lane & 15, c4 = lane >> 4;
  f32x4 acc[4][2];
  f32x4 z = {0.f, 0.f, 0.f, 0.f};
#pragma unroll
  for (int mf = 0; mf < 4; ++mf)
#pragma unroll
    for (int nf = 0; nf < 2; ++nf) acc[mf][nf] = z;
#pragma unroll
  for (int kc = 0; kc < 8; ++kc) {
    bf16x8 a[4], bb[2];
#pragma unroll
    for (int mf = 0; mf < 4; ++mf)
      a[mf] = *reinterpret_cast<const bf16x8*>(OS + swz256(16 * mf + r16, 32 * kc + 8 * c4));
#pragma unroll
    for (int nf = 0; nf < 2; ++nf)
      bb[nf] = *reinterpret_cast<const bf16x8*>(pw + nf * 4096 + kc * 512 + lane * 8);
#pragma unroll
    for (int mf = 0; mf < 4; ++mf)
#pragma unroll
      for (int nf = 0; nf < 2; ++nf) acc[mf][nf] = mfma16(a[mf], bb[nf], acc[mf][nf]);
  }
#pragma unroll
  for (int nf = 0; nf < 2; ++nf) {
    float bb = bias[32 * w + 16 * nf + r16];
#pragma unroll
    for (int mf = 0; mf < 4; ++mf)
#pragma unroll
      for (int r = 0; r < 4; ++r)
        dst[(16 * mf + 4 * c4 + r) * 256 + 32 * w + 16 * nf + r16] = acc[mf][nf][r] + bb;
  }
}

// ---------------- main fused kernel: one block per window, 8 waves ----------
// LDS: A(64K fp32), B(64K fp32), OS(32K bf16). Async 1-ahead staging:
//  P0: gll A<-q                          P5: Vs(B)+PV->OS
//  P1: gll B<-k;  projT Q(A)             P6: outProj_s(OS)
//  P2: gll A<-v;  projT K(B); attn       P7: Vh(A)+PV->OS
//  P3: gll B<-sc; V(A)+PV->OS            P8: outProj_h(OS)
//  P4: gll A<-sh; outProj_x(OS)
__global__ __launch_bounds__(512, 2) void win_attn(
    const float* __restrict__ gq, const float* __restrict__ gk, const float* __restrict__ gv,
    const float* __restrict__ gsc, const float* __restrict__ gsh,
    const unsigned short* __restrict__ pk,
    const float* __restrict__ b_q, const float* __restrict__ b_k, const float* __restrict__ b_v,
    const float* __restrict__ b_vs, const float* __restrict__ b_vh,
    const float* __restrict__ b_px, const float* __restrict__ b_ps, const float* __restrict__ b_ph,
    const float* __restrict__ bmt, float* __restrict__ out) {
  __shared__ __align__(16) char smraw[163840];          // 160 KiB exactly
  float* A  = (float*)smraw;                            // 64 KiB fp32 tile
  float* Bt = (float*)(smraw + 65536);                  // 64 KiB fp32 tile
  unsigned short* OS = (unsigned short*)(smraw + 131072); // 32 KiB bf16 O tile

  const int b    = blockIdx.x;
  const int tid  = threadIdx.x;
  const int lane = tid & 63;
  const int w    = tid >> 6;          // wave id == head id
  const int wi   = b & 63;

  bf16x8 Qf[4], Kf[4], Pf[4][2], Vf[2][2];

  // P0: async q -> A
  issue_tile(gq, b, A, w, lane);
  __syncthreads();                                      // bar0 (drains q)

  // P1: async k -> B (overlaps compute); projT Q (A)
  issue_tile(gk, b, Bt, w, lane);
  __builtin_amdgcn_sched_barrier(0);
  projT_head_f32(A, pwBase(pk, 0, w), b_q, 0.17677669529663687f, lane, w, Qf);
  __syncthreads();                                      // bar1 (drains k)

  // P2: async v -> A (q dead); projT K (B); attention -> Pf
  issue_tile(gv, b, A, w, lane);
  __builtin_amdgcn_sched_barrier(0);
  projT_head_f32(Bt, pwBase(pk, 1, w), b_k, 1.0f, lane, w, Kf);
  attn_head(Qf, Kf, bmt + ((size_t)(wi * 8 + w) << 12), lane, Pf);
  __syncthreads();                                      // bar2 (drains v)

  // P3: async sc -> B (k dead); V proj (A) + PV -> OS
  issue_tile(gsc, b, Bt, w, lane);
  __builtin_amdgcn_sched_barrier(0);
  {
    f32x4 acc[4][2];
    projN32_f32(A, pwBase(pk, 2, w), lane, acc);
    vFrag(acc, b_v, lane, w, Vf);
  }
  pv_store(Pf, Vf, OS, lane, w);
  __syncthreads();                                      // bar3 (drains sc)

  // P4: async sh -> A (v dead); outProj_x (OS)
  issue_tile(gsh, b, A, w, lane);
  __builtin_amdgcn_sched_barrier(0);
  outProj(OS, pwBase(pk, 5, w), b_px, out + (size_t)b * 16384, lane, w);
  __syncthreads();                                      // bar4 (drains sh)

  // P5: Vs proj (B) + PV -> OS (O_x dead)
  {
    f32x4 acc[4][2];
    projN32_f32(Bt, pwBase(pk, 3, w), lane, acc);
    vFrag(acc, b_vs, lane, w, Vf);
  }
  pv_store(Pf, Vf, OS, lane, w);
  __syncthreads();                                      // bar5

  // P6: outProj_s (OS)
  outProj(OS, pwBase(pk, 6, w), b_ps, out + 16777216 + (size_t)b * 16384, lane, w);
  __syncthreads();                                      // bar6

  // P7: Vh proj (A) + PV -> OS (O_s dead)
  {
    f32x4 acc[4][2];
    projN32_f32(A, pwBase(pk, 4, w), lane, acc);
    vFrag(acc, b_vh, lane, w, Vf);
  }
  pv_store(Pf, Vf, OS, lane, w);
  __syncthreads();                                      // bar7

  // P8: outProj_h (OS)
  outProj(OS, pwBase(pk, 7, w), b_ph, out + 33554432 + (size_t)b * 16384, lane, w);
}

// ---------------------------------------------------------------------------
extern "C" void kernel_launch(void* const* d_in, const int* in_sizes, int n_in,
                              void* d_out, int out_size, void* d_ws, size_t ws_size,
                              hipStream_t stream) {
  const float* Xq   = (const float*)d_in[0];
  const float* Xk   = (const float*)d_in[1];
  const float* Xv   = (const float*)d_in[2];
  const float* Xsc  = (const float*)d_in[3];
  const float* Xsh  = (const float*)d_in[4];
  const float* mask = (const float*)d_in[5];
  const float* Wq   = (const float*)d_in[6];  const float* bq  = (const float*)d_in[7];
  const float* Wk   = (const float*)d_in[8];  const float* bk  = (const float*)d_in[9];
  const float* Wv   = (const float*)d_in[10]; const float* bv  = (const float*)d_in[11];
  const float* Wvs  = (const float*)d_in[12]; const float* bvs = (const float*)d_in[13];
  const float* Wvh  = (const float*)d_in[14]; const float* bvh = (const float*)d_in[15];
  const float* Wpx  = (const float*)d_in[16]; const float* bpx = (const float*)d_in[17];
  const float* Wps  = (const float*)d_in[18]; const float* bps = (const float*)d_in[19];
  const float* Wph  = (const float*)d_in[20]; const float* bph = (const float*)d_in[21];
  const float* btab = (const float*)d_in[22];
  const int*   ridx = (const int*)d_in[23];

  unsigned short* pk = (unsigned short*)d_ws;                  // 8 mats x 128KB = 1 MB
  float* bmt = (float*)((char*)d_ws + (size_t)8 * 65536 * 2);  // 2M floats = 8 MB

  pack_weights<<<256, 256, 0, stream>>>(Wq, Wk, Wv, Wvs, Wvh, Wpx, Wps, Wph, pk);
  make_bmt<<<8192, 256, 0, stream>>>(mask, btab, ridx, bmt);
  win_attn<<<1024, 512, 0, stream>>>(Xq, Xk, Xv, Xsc, Xsh, pk,
                                     bq, bk, bv, bvs, bvh, bpx, bps, bph,
                                     bmt, (float*)d_out);
}